// Round 1
// baseline (265.896 us; speedup 1.0000x reference)
//
#include <hip/hip_runtime.h>
#include <hip/hip_bf16.h>
#include <math.h>

typedef __bf16 bf16x8 __attribute__((ext_vector_type(8)));
typedef float  floatx4 __attribute__((ext_vector_type(4)));

// Workspace layout (bytes):
//   Kmat bf16 [2][8192][16]   offset 0        size 524288
//   Vtg  bf16 [2][32][8192]   offset 524288   size 1048576
#define KMAT_ELEMS (2 * 8192 * 16)

// ---------------- Kernel A: projections ----------------
// one wg per (b, h, w): X = in[b,:,hw,:] (32l x 32c)
// x1[o][c] = W1[o,:]·X[:,c] + b1[o]  -> Kmat[b][i][k], k=c>>1, i=(c&1)*4096+o*256+hw
// x2[o][c] = W2[o,:]·X[:,c] + b2[o]  -> Vtg[b][c][i],  i=o*256+hw
__global__ __launch_bounds__(256) void proj_kernel(
    const float* __restrict__ in, const float* __restrict__ W1,
    const float* __restrict__ b1, const float* __restrict__ W2,
    const float* __restrict__ b2,
    __hip_bfloat16* __restrict__ Kmat, __hip_bfloat16* __restrict__ Vtg)
{
    __shared__ float Xs[32][32];
    const int t = threadIdx.x;
    const int bid = blockIdx.x;       // 0..511
    const int b = bid >> 8;
    const int hw = bid & 255;

    {
        int l = t >> 3, cs = (t & 7) * 4;
        float4 v = *(const float4*)(in + (((size_t)b * 32 + l) * 256 + hw) * 32 + cs);
        *(float4*)&Xs[l][cs] = v;
    }
    __syncthreads();

    const int c = t & 31;
    const int g = t >> 5;             // 0..7

#pragma unroll
    for (int oo = 0; oo < 2; ++oo) {
        int o = g * 2 + oo;           // 0..15
        float acc = b1[o];
#pragma unroll
        for (int l = 0; l < 32; ++l) acc += W1[o * 32 + l] * Xs[l][c];
        int k = c >> 1;
        int i = (c & 1) * 4096 + o * 256 + hw;
        Kmat[((size_t)b * 8192 + i) * 16 + k] = __float2bfloat16(acc);
    }
#pragma unroll
    for (int oo = 0; oo < 4; ++oo) {
        int o = g * 4 + oo;           // 0..31
        float acc = b2[o];
#pragma unroll
        for (int l = 0; l < 32; ++l) acc += W2[o * 32 + l] * Xs[l][c];
        int i = o * 256 + hw;
        Vtg[((size_t)b * 32 + c) * 8192 + i] = __float2bfloat16(acc);
    }
}

// ---------------- Kernel B: flash attention ----------------
// grid 256: b = bid>>7, i-tile of 64 rows. block 256 (4 waves), wave = 16-row strip.
__global__ __launch_bounds__(256) void flash_kernel(
    const __hip_bfloat16* __restrict__ Kmat, const __hip_bfloat16* __restrict__ Vtg,
    const float* __restrict__ in, const float* __restrict__ gamma,
    float* __restrict__ out)
{
    // LDS: padded strides keep b128 reads 16B-aligned and <=2-way bank conflicts
    __shared__ __hip_bfloat16 Ks[64 * 40];        // [j][k], k0..15 real, 16..39 zero; stride 40 (80B)
    __shared__ __hip_bfloat16 Vt[32 * 72];        // [c][j], stride 72 (144B)
    __shared__ __hip_bfloat16 Ps[4][16 * 72];     // per-wave P [row][j], stride 72

    const int t = threadIdx.x;
    const int lane = t & 63;
    const int wv = t >> 6;            // wave 0..3
    const int m = lane & 15;
    const int q = lane >> 4;          // quad 0..3

    const int bid = blockIdx.x;       // 0..255
    const int b = bid >> 7;
    const int i0 = (bid & 127) * 64;

    // zero the k=16..39 pad region of Ks once (never overwritten afterwards)
    if (t < 192) {
        int j = t / 3, part = t % 3;
        *(float4*)((char*)Ks + j * 80 + 32 + part * 16) = make_float4(0.f, 0.f, 0.f, 0.f);
    }

    // Q A-frag: A[m][k]: m=lane&15 -> row i0+wv*16+m ; k=quad*8+j ; quads 2,3 = zero pad
    bf16x8 aq = {};
    if (q < 2) {
        aq = *(const bf16x8*)(Kmat + ((size_t)b * 8192 + i0 + wv * 16 + m) * 16 + q * 8);
    }

    float m_prev[4], l_run[4];
    floatx4 o_acc[2];
#pragma unroll
    for (int r = 0; r < 4; ++r) { m_prev[r] = -INFINITY; l_run[r] = 0.f; }
    o_acc[0] = (floatx4){0.f, 0.f, 0.f, 0.f};
    o_acc[1] = (floatx4){0.f, 0.f, 0.f, 0.f};

    const __hip_bfloat16* Kb = Kmat + (size_t)b * 8192 * 16;
    const __hip_bfloat16* Vb = Vtg + (size_t)b * 32 * 8192;

    for (int jt = 0; jt < 128; ++jt) {
        const int j0 = jt * 64;
        __syncthreads();   // previous tile's reads done before restaging
        // stage Vt tile: all 256 threads, one b128 each
        {
            int c = t >> 3, seg = t & 7;
            float4 v = *(const float4*)(Vb + (size_t)c * 8192 + j0 + seg * 8);
            *(float4*)((char*)Vt + c * 144 + seg * 16) = v;
        }
        // stage Ks tile: threads < 128, one b128 each (16 real k = 32B/row)
        if (t < 128) {
            int j = t >> 1, half = t & 1;
            float4 v = *(const float4*)(Kb + (size_t)(j0 + j) * 16 + half * 8);
            *(float4*)((char*)Ks + j * 80 + half * 16) = v;
        }
        __syncthreads();

        // S strip (16 x 64) = Q(16x32,padded) x K^T : 4 n-tiles
        floatx4 s[4];
#pragma unroll
        for (int nt = 0; nt < 4; ++nt) {
            bf16x8 bk = *(const bf16x8*)((char*)Ks + (nt * 16 + m) * 80 + q * 16);
            s[nt] = __builtin_amdgcn_mfma_f32_16x16x32_bf16(
                        aq, bk, (floatx4){0.f, 0.f, 0.f, 0.f}, 0, 0, 0);
        }

        // online softmax: row r = q*4+reg lives in the 16 lanes of this quad group
        float p[4][4];
#pragma unroll
        for (int r = 0; r < 4; ++r) {
            float mx = fmaxf(fmaxf(s[0][r], s[1][r]), fmaxf(s[2][r], s[3][r]));
#pragma unroll
            for (int off = 8; off > 0; off >>= 1)
                mx = fmaxf(mx, __shfl_xor(mx, off, 16));
            float mn = fmaxf(m_prev[r], mx);
            float alpha = __expf(m_prev[r] - mn);
            float rs = 0.f;
#pragma unroll
            for (int nt = 0; nt < 4; ++nt) {
                float e = __expf(s[nt][r] - mn);
                p[nt][r] = e;
                rs += e;
            }
#pragma unroll
            for (int off = 8; off > 0; off >>= 1)
                rs += __shfl_xor(rs, off, 16);
            l_run[r] = l_run[r] * alpha + rs;
            m_prev[r] = mn;
            o_acc[0][r] *= alpha;
            o_acc[1][r] *= alpha;
        }

        // P -> per-wave LDS (C-layout scatter), then read back in A-layout
#pragma unroll
        for (int nt = 0; nt < 4; ++nt)
#pragma unroll
            for (int r = 0; r < 4; ++r)
                Ps[wv][(q * 4 + r) * 72 + nt * 16 + m] = __float2bfloat16(p[nt][r]);

        // O(16x32) += P(16x64) x V(64x32): 2 k-chunks x 2 n-tiles
#pragma unroll
        for (int kc = 0; kc < 2; ++kc) {
            bf16x8 ap = *(const bf16x8*)((char*)&Ps[wv][0] + m * 144 + kc * 64 + q * 16);
#pragma unroll
            for (int nt = 0; nt < 2; ++nt) {
                bf16x8 bv = *(const bf16x8*)((char*)Vt + (nt * 16 + m) * 144 + kc * 64 + q * 16);
                o_acc[nt] = __builtin_amdgcn_mfma_f32_16x16x32_bf16(ap, bv, o_acc[nt], 0, 0, 0);
            }
        }
    }

    // epilogue: out = (O/l)*gamma + in  ; flat index = b*262144 + i*32 + c
    const float gm = gamma[0];
#pragma unroll
    for (int nt = 0; nt < 2; ++nt) {
#pragma unroll
        for (int r = 0; r < 4; ++r) {
            int ig = i0 + wv * 16 + q * 4 + r;
            int c = nt * 16 + m;
            size_t idx = (size_t)b * 262144 + (size_t)ig * 32 + c;
            out[idx] = (o_acc[nt][r] / l_run[r]) * gm + in[idx];
        }
    }
}

extern "C" void kernel_launch(void* const* d_in, const int* in_sizes, int n_in,
                              void* d_out, int out_size, void* d_ws, size_t ws_size,
                              hipStream_t stream) {
    const float* in = (const float*)d_in[0];
    const float* W1 = (const float*)d_in[1];
    const float* b1 = (const float*)d_in[2];
    const float* W2 = (const float*)d_in[3];
    const float* b2 = (const float*)d_in[4];
    const float* gamma = (const float*)d_in[5];
    float* out = (float*)d_out;

    __hip_bfloat16* Kmat = (__hip_bfloat16*)d_ws;
    __hip_bfloat16* Vtg = Kmat + KMAT_ELEMS;

    proj_kernel<<<512, 256, 0, stream>>>(in, W1, b1, W2, b2, Kmat, Vtg);
    flash_kernel<<<256, 256, 0, stream>>>(Kmat, Vtg, in, gamma, out);
}

// Round 2
// 172.628 us; speedup vs baseline: 1.5403x; 1.5403x over previous
//
#include <hip/hip_runtime.h>
#include <hip/hip_bf16.h>
#include <math.h>

typedef __bf16 bf16x8 __attribute__((ext_vector_type(8)));
typedef float  floatx4 __attribute__((ext_vector_type(4)));

// Workspace layout (bytes):
//   Kmat  bf16  [2][8192][16]              offset 0        size 524288
//   Vtg   bf16  [2][32][8192]              offset 524288   size 1048576
//   Opart f32   [2*8192][split][32]        offset 1572864
//   Ml    f32   [2*8192][split][2]         after Opart
#define KMAT_ELEMS (2 * 8192 * 16)
#define VTG_ELEMS (2 * 32 * 8192)
#define PART_OFF 1572864

// ---------------- Kernel A: projections ----------------
__global__ __launch_bounds__(256) void proj_kernel(
    const float* __restrict__ in, const float* __restrict__ W1,
    const float* __restrict__ b1, const float* __restrict__ W2,
    const float* __restrict__ b2,
    __hip_bfloat16* __restrict__ Kmat, __hip_bfloat16* __restrict__ Vtg)
{
    __shared__ float Xs[32][32];
    __shared__ float W1s[16 * 32];
    __shared__ float W2s[32 * 32];
    const int t = threadIdx.x;
    const int bid = blockIdx.x;       // 0..511
    const int b = bid >> 8;
    const int hw = bid & 255;

    {
        int l = t >> 3, cs = (t & 7) * 4;
        float4 v = *(const float4*)(in + (((size_t)b * 32 + l) * 256 + hw) * 32 + cs);
        *(float4*)&Xs[l][cs] = v;
    }
    if (t < 128) *(float4*)&W1s[t * 4] = *(const float4*)(W1 + t * 4);
    *(float4*)&W2s[t * 4] = *(const float4*)(W2 + t * 4);
    __syncthreads();

    const int c = t & 31;
    const int g = t >> 5;             // 0..7

#pragma unroll
    for (int oo = 0; oo < 2; ++oo) {
        int o = g * 2 + oo;           // 0..15
        float acc = b1[o];
#pragma unroll
        for (int l = 0; l < 32; ++l) acc += W1s[o * 32 + l] * Xs[l][c];
        int k = c >> 1;
        int i = (c & 1) * 4096 + o * 256 + hw;
        Kmat[((size_t)b * 8192 + i) * 16 + k] = __float2bfloat16(acc);
    }
#pragma unroll
    for (int oo = 0; oo < 4; ++oo) {
        int o = g * 4 + oo;           // 0..31
        float acc = b2[o];
#pragma unroll
        for (int l = 0; l < 32; ++l) acc += W2s[o * 32 + l] * Xs[l][c];
        int i = o * 256 + hw;
        Vtg[((size_t)b * 32 + c) * 8192 + i] = __float2bfloat16(acc);
    }
}

// ---------------- Kernel B: flash attention, split-j (flash-decoding) ----------------
// grid = 2 * 128 * split. bid -> s = bid & (split-1), itile = (bid>>lsplit)&127,
// b = bid >> (lsplit+7). Each block: 64 i-rows, j-chunk of (8192>>lsplit).
__global__ __launch_bounds__(256) void flash_split_kernel(
    const __hip_bfloat16* __restrict__ Kmat, const __hip_bfloat16* __restrict__ Vtg,
    float* __restrict__ Opart, float* __restrict__ Ml, int lsplit)
{
    __shared__ __hip_bfloat16 Ks[64 * 40];        // [j][k], k0..15 real, 16..39 zero pad
    __shared__ __hip_bfloat16 Vt[32 * 72];        // [c][j], stride 72
    __shared__ __hip_bfloat16 Ps[4][16 * 72];     // per-wave P [row][j], stride 72

    const int t = threadIdx.x;
    const int lane = t & 63;
    const int wv = t >> 6;            // wave 0..3
    const int m = lane & 15;
    const int q = lane >> 4;          // quad 0..3

    const int bid = blockIdx.x;
    const int split = 1 << lsplit;
    const int s = bid & (split - 1);
    const int itile = (bid >> lsplit) & 127;
    const int b = bid >> (lsplit + 7);
    const int i0 = itile * 64;
    const int ntiles = 128 >> lsplit;

    if (t < 192) {
        int j = t / 3, part = t % 3;
        *(float4*)((char*)Ks + j * 80 + 32 + part * 16) = make_float4(0.f, 0.f, 0.f, 0.f);
    }

    bf16x8 aq = {};
    if (q < 2) {
        aq = *(const bf16x8*)(Kmat + ((size_t)b * 8192 + i0 + wv * 16 + m) * 16 + q * 8);
    }

    float m_prev[4], l_run[4];
    floatx4 o_acc[2];
#pragma unroll
    for (int r = 0; r < 4; ++r) { m_prev[r] = -INFINITY; l_run[r] = 0.f; }
    o_acc[0] = (floatx4){0.f, 0.f, 0.f, 0.f};
    o_acc[1] = (floatx4){0.f, 0.f, 0.f, 0.f};

    const __hip_bfloat16* Kb = Kmat + (size_t)b * 8192 * 16;
    const __hip_bfloat16* Vb = Vtg + (size_t)b * 32 * 8192;

    for (int jt = 0; jt < ntiles; ++jt) {
        const int j0 = (s * ntiles + jt) * 64;
        __syncthreads();
        {
            int c = t >> 3, seg = t & 7;
            float4 v = *(const float4*)(Vb + (size_t)c * 8192 + j0 + seg * 8);
            *(float4*)((char*)Vt + c * 144 + seg * 16) = v;
        }
        if (t < 128) {
            int j = t >> 1, half = t & 1;
            float4 v = *(const float4*)(Kb + (size_t)(j0 + j) * 16 + half * 8);
            *(float4*)((char*)Ks + j * 80 + half * 16) = v;
        }
        __syncthreads();

        floatx4 sacc[4];
#pragma unroll
        for (int nt = 0; nt < 4; ++nt) {
            bf16x8 bk = *(const bf16x8*)((char*)Ks + (nt * 16 + m) * 80 + q * 16);
            sacc[nt] = __builtin_amdgcn_mfma_f32_16x16x32_bf16(
                        aq, bk, (floatx4){0.f, 0.f, 0.f, 0.f}, 0, 0, 0);
        }

        float p[4][4];
#pragma unroll
        for (int r = 0; r < 4; ++r) {
            float mx = fmaxf(fmaxf(sacc[0][r], sacc[1][r]), fmaxf(sacc[2][r], sacc[3][r]));
#pragma unroll
            for (int off = 8; off > 0; off >>= 1)
                mx = fmaxf(mx, __shfl_xor(mx, off, 16));
            float mn = fmaxf(m_prev[r], mx);
            float alpha = __expf(m_prev[r] - mn);
            float rs = 0.f;
#pragma unroll
            for (int nt = 0; nt < 4; ++nt) {
                float e = __expf(sacc[nt][r] - mn);
                p[nt][r] = e;
                rs += e;
            }
#pragma unroll
            for (int off = 8; off > 0; off >>= 1)
                rs += __shfl_xor(rs, off, 16);
            l_run[r] = l_run[r] * alpha + rs;
            m_prev[r] = mn;
            o_acc[0][r] *= alpha;
            o_acc[1][r] *= alpha;
        }

#pragma unroll
        for (int nt = 0; nt < 4; ++nt)
#pragma unroll
            for (int r = 0; r < 4; ++r)
                Ps[wv][(q * 4 + r) * 72 + nt * 16 + m] = __float2bfloat16(p[nt][r]);

#pragma unroll
        for (int kc = 0; kc < 2; ++kc) {
            bf16x8 ap = *(const bf16x8*)((char*)&Ps[wv][0] + m * 144 + kc * 64 + q * 16);
#pragma unroll
            for (int nt = 0; nt < 2; ++nt) {
                bf16x8 bv = *(const bf16x8*)((char*)Vt + (nt * 16 + m) * 144 + kc * 64 + q * 16);
                o_acc[nt] = __builtin_amdgcn_mfma_f32_16x16x32_bf16(ap, bv, o_acc[nt], 0, 0, 0);
            }
        }
    }

    // write partials: Opart[row][s][c], Ml[row][s][{m,l}]
#pragma unroll
    for (int nt = 0; nt < 2; ++nt) {
#pragma unroll
        for (int r = 0; r < 4; ++r) {
            size_t row = (size_t)b * 8192 + i0 + wv * 16 + q * 4 + r;
            Opart[((row << lsplit) | s) * 32 + nt * 16 + m] = o_acc[nt][r];
        }
    }
    if (m == 0) {
#pragma unroll
        for (int r = 0; r < 4; ++r) {
            size_t row = (size_t)b * 8192 + i0 + wv * 16 + q * 4 + r;
            Ml[(((row << lsplit) | s) << 1) + 0] = m_prev[r];
            Ml[(((row << lsplit) | s) << 1) + 1] = l_run[r];
        }
    }
}

// ---------------- Kernel C: combine partials + epilogue ----------------
// grid 2048 x 256: thread -> (row = bid*8 + t>>5, c = t&31)
__global__ __launch_bounds__(256) void combine_kernel(
    const float* __restrict__ Opart, const float* __restrict__ Ml,
    const float* __restrict__ in, const float* __restrict__ gamma,
    float* __restrict__ out, int lsplit)
{
    const int t = threadIdx.x;
    const int c = t & 31;
    const size_t row = (size_t)blockIdx.x * 8 + (t >> 5);
    const int split = 1 << lsplit;

    float mstar = -INFINITY;
    for (int s = 0; s < split; ++s)
        mstar = fmaxf(mstar, Ml[(((row << lsplit) | s) << 1)]);
    float acc = 0.f, l = 0.f;
    for (int s = 0; s < split; ++s) {
        float ms = Ml[(((row << lsplit) | s) << 1)];
        float ls = Ml[(((row << lsplit) | s) << 1) + 1];
        float a = __expf(ms - mstar);
        acc += a * Opart[((row << lsplit) | s) * 32 + c];
        l += a * ls;
    }
    size_t idx = row * 32 + c;
    out[idx] = (acc / l) * gamma[0] + in[idx];
}

extern "C" void kernel_launch(void* const* d_in, const int* in_sizes, int n_in,
                              void* d_out, int out_size, void* d_ws, size_t ws_size,
                              hipStream_t stream) {
    const float* in = (const float*)d_in[0];
    const float* W1 = (const float*)d_in[1];
    const float* b1 = (const float*)d_in[2];
    const float* W2 = (const float*)d_in[3];
    const float* b2 = (const float*)d_in[4];
    const float* gamma = (const float*)d_in[5];
    float* out = (float*)d_out;

    __hip_bfloat16* Kmat = (__hip_bfloat16*)d_ws;
    __hip_bfloat16* Vtg = Kmat + KMAT_ELEMS;

    // pick largest split (pow2 <= 8) that fits in ws
    int lsplit = 3;
    while (lsplit > 0) {
        size_t need = (size_t)PART_OFF
                    + (((size_t)16384 << lsplit) * 32 + ((size_t)16384 << lsplit) * 2) * 4;
        if (need <= ws_size) break;
        --lsplit;
    }
    float* Opart = (float*)((char*)d_ws + PART_OFF);
    float* Ml = Opart + ((size_t)16384 << lsplit) * 32;

    proj_kernel<<<512, 256, 0, stream>>>(in, W1, b1, W2, b2, Kmat, Vtg);
    flash_split_kernel<<<2 * 128 * (1 << lsplit), 256, 0, stream>>>(Kmat, Vtg, Opart, Ml, lsplit);
    combine_kernel<<<2048, 256, 0, stream>>>(Opart, Ml, in, gamma, out, lsplit);
}

// Round 3
// 159.628 us; speedup vs baseline: 1.6657x; 1.0814x over previous
//
#include <hip/hip_runtime.h>
#include <hip/hip_bf16.h>
#include <math.h>

typedef __bf16 bf16x8 __attribute__((ext_vector_type(8)));
typedef __bf16 bf16x4v __attribute__((ext_vector_type(4)));
typedef short  s16x4  __attribute__((ext_vector_type(4)));
typedef float  floatx16 __attribute__((ext_vector_type(16)));

// Workspace layout (bytes):
//   Kmat bf16 [2][8192][16]   offset 0        (512 KB)   unscaled
//   Qmat bf16 [2][8192][16]   offset 524288   (512 KB)   scaled by log2(e)
//   Vtg  bf16 [2][32][8192]   offset 1048576  (1 MB)
//   Opart f32 [2*8192][split][32]  offset 2097152
//   Lpart f32 [2*8192][split]      after Opart
#define KQ_ELEMS (2 * 8192 * 16)
#define PART_OFF 2097152

// ---------------- Kernel A: projections ----------------
__global__ __launch_bounds__(256) void proj_kernel(
    const float* __restrict__ in, const float* __restrict__ W1,
    const float* __restrict__ b1, const float* __restrict__ W2,
    const float* __restrict__ b2,
    __hip_bfloat16* __restrict__ Kmat, __hip_bfloat16* __restrict__ Qmat,
    __hip_bfloat16* __restrict__ Vtg)
{
    __shared__ float Xs[32][32];
    __shared__ float W1s[16 * 32];
    __shared__ float W2s[32 * 32];
    const int t = threadIdx.x;
    const int bid = blockIdx.x;       // 0..511
    const int b = bid >> 8;
    const int hw = bid & 255;

    {
        int l = t >> 3, cs = (t & 7) * 4;
        float4 v = *(const float4*)(in + (((size_t)b * 32 + l) * 256 + hw) * 32 + cs);
        *(float4*)&Xs[l][cs] = v;
    }
    if (t < 128) *(float4*)&W1s[t * 4] = *(const float4*)(W1 + t * 4);
    *(float4*)&W2s[t * 4] = *(const float4*)(W2 + t * 4);
    __syncthreads();

    const int c = t & 31;
    const int g = t >> 5;             // 0..7

#pragma unroll
    for (int oo = 0; oo < 2; ++oo) {
        int o = g * 2 + oo;           // 0..15
        float acc = b1[o];
#pragma unroll
        for (int l = 0; l < 32; ++l) acc += W1s[o * 32 + l] * Xs[l][c];
        int k = c >> 1;
        int i = (c & 1) * 4096 + o * 256 + hw;
        size_t idx = ((size_t)b * 8192 + i) * 16 + k;
        Kmat[idx] = __float2bfloat16(acc);
        Qmat[idx] = __float2bfloat16(acc * 1.4426950408889634f);
    }
#pragma unroll
    for (int oo = 0; oo < 4; ++oo) {
        int o = g * 4 + oo;           // 0..31
        float acc = b2[o];
#pragma unroll
        for (int l = 0; l < 32; ++l) acc += W2s[o * 32 + l] * Xs[l][c];
        int i = o * 256 + hw;
        Vtg[((size_t)b * 32 + c) * 8192 + i] = __float2bfloat16(acc);
    }
}

// ---------------- Kernel B: flash attention, LDS-free, no-max softmax ----------------
// block = 256 thr (4 waves), each wave owns 32 i-rows. grid = 2 * 64 * split.
// Per 32-j iteration:
//   S^T(32j x 32i) = K_rows(A) x Q_rows(B) via mfma_32x32x16_bf16 (K=16, no pad)
//   P = exp2(S')  (Q pre-scaled by log2 e)  -- P regs ARE the 32x32x8 A-layout
//   O(32i x 32c) += P x V via 4x mfma_32x32x8bf16_1k, V b64 straight from global
__global__ __launch_bounds__(256) void flash_kernel(
    const __hip_bfloat16* __restrict__ Kmat, const __hip_bfloat16* __restrict__ Qmat,
    const __hip_bfloat16* __restrict__ Vtg,
    float* __restrict__ Opart, float* __restrict__ Lpart, int lsplit)
{
    const int t = threadIdx.x;
    const int lane = t & 63;
    const int wv = t >> 6;            // 0..3
    const int m = lane & 31;          // i-col (S) / c-col (O) / row selector for A-frags
    const int h = lane >> 5;          // half 0/1

    const int bid = blockIdx.x;
    const int split = 1 << lsplit;
    const int s = bid & (split - 1);
    const int itile = (bid >> lsplit) & 63;
    const int b = bid >> (lsplit + 6);
    const int i0 = itile * 128 + wv * 32;
    const int jcount = 8192 >> lsplit;
    const int jbase = s * jcount;
    const int niter = jcount >> 5;

    const __hip_bfloat16* Kb = Kmat + (size_t)b * 8192 * 16;
    const __hip_bfloat16* Vb = Vtg + (size_t)b * 32 * 8192 + (size_t)m * 8192;

    // Q B-frag (held in regs): B[k=8h+idx][n=m] = Q'[i0+m][8h+idx]
    const bf16x8 bq = *(const bf16x8*)(Qmat + ((size_t)b * 8192 + i0 + m) * 16 + h * 8);

    floatx16 o_acc = {};
    float l = 0.f;

#pragma unroll 2
    for (int it = 0; it < niter; ++it) {
        const int j = jbase + it * 32;
        // K A-frag: A[m'=j_loc][k=8h+idx] = K[j+m'][8h+idx]
        bf16x8 ak = *(const bf16x8*)(Kb + (size_t)(j + m) * 16 + h * 8);
        floatx16 sc = __builtin_amdgcn_mfma_f32_32x32x16_bf16(ak, bq, (floatx16){}, 0, 0, 0);

        // P = 2^sc ; reg 4g+idx holds j_loc = g*8 + 4h + idx  == 32x32x8 A-layout
#pragma unroll
        for (int g = 0; g < 4; ++g) {
            bf16x4v pb;
#pragma unroll
            for (int idx = 0; idx < 4; ++idx) {
                float e = __builtin_amdgcn_exp2f(sc[4 * g + idx]);
                l += e;
                pb[idx] = (__bf16)e;
            }
            // V B-frag: B[k=4h+idx][n=m] = V[j + g*8 + 4h + idx][c=m] from Vt[c][j]
            s16x4 vf = *(const s16x4*)(Vb + j + g * 8 + h * 4);
            o_acc = __builtin_amdgcn_mfma_f32_32x32x8bf16_1k(
                        __builtin_bit_cast(s16x4, pb), vf, o_acc, 0, 0, 0);
        }
    }

    // finalize l: halves hold disjoint j classes
    l += __shfl_xor(l, 32);

    // write partials. o_acc reg r -> row i_loc=(r&3)+8*(r>>2)+4h, col c=m
#pragma unroll
    for (int r = 0; r < 16; ++r) {
        int iloc = (r & 3) + 8 * (r >> 2) + 4 * h;
        size_t row = (size_t)b * 8192 + i0 + iloc;
        Opart[((row << lsplit) | s) * 32 + m] = o_acc[r];
    }
    if (h == 0)
        Lpart[(((size_t)b * 8192 + i0 + m) << lsplit) | s] = l;
}

// ---------------- Kernel C: combine partials + epilogue ----------------
__global__ __launch_bounds__(256) void combine_kernel(
    const float* __restrict__ Opart, const float* __restrict__ Lpart,
    const float* __restrict__ in, const float* __restrict__ gamma,
    float* __restrict__ out, int lsplit)
{
    const int t = threadIdx.x;
    const int c = t & 31;
    const size_t row = (size_t)blockIdx.x * 8 + (t >> 5);
    const int split = 1 << lsplit;

    float acc = 0.f, l = 0.f;
    for (int s = 0; s < split; ++s) {
        acc += Opart[((row << lsplit) | s) * 32 + c];
        l += Lpart[(row << lsplit) | s];
    }
    size_t idx = row * 32 + c;
    out[idx] = (acc / l) * gamma[0] + in[idx];
}

extern "C" void kernel_launch(void* const* d_in, const int* in_sizes, int n_in,
                              void* d_out, int out_size, void* d_ws, size_t ws_size,
                              hipStream_t stream) {
    const float* in = (const float*)d_in[0];
    const float* W1 = (const float*)d_in[1];
    const float* b1 = (const float*)d_in[2];
    const float* W2 = (const float*)d_in[3];
    const float* b2 = (const float*)d_in[4];
    const float* gamma = (const float*)d_in[5];
    float* out = (float*)d_out;

    __hip_bfloat16* Kmat = (__hip_bfloat16*)d_ws;
    __hip_bfloat16* Qmat = Kmat + KQ_ELEMS;
    __hip_bfloat16* Vtg = Qmat + KQ_ELEMS;

    // pick largest split (pow2 <= 16) whose partials fit in ws
    int lsplit = 4;
    while (lsplit > 1) {
        size_t need = (size_t)PART_OFF + ((size_t)16384 << lsplit) * 33 * 4;
        if (need <= ws_size) break;
        --lsplit;
    }
    float* Opart = (float*)((char*)d_ws + PART_OFF);
    float* Lpart = Opart + ((size_t)16384 << lsplit) * 32;

    proj_kernel<<<512, 256, 0, stream>>>(in, W1, b1, W2, b2, Kmat, Qmat, Vtg);
    flash_kernel<<<2 * 64 * (1 << lsplit), 256, 0, stream>>>(Kmat, Qmat, Vtg, Opart, Lpart, lsplit);
    combine_kernel<<<2048, 256, 0, stream>>>(Opart, Lpart, in, gamma, out, lsplit);
}

// Round 4
// 115.567 us; speedup vs baseline: 2.3008x; 1.3813x over previous
//
#include <hip/hip_runtime.h>
#include <hip/hip_bf16.h>
#include <math.h>

typedef __bf16 bf16x8 __attribute__((ext_vector_type(8)));
typedef __bf16 bf16x4v __attribute__((ext_vector_type(4)));
typedef short  s16x4  __attribute__((ext_vector_type(4)));
typedef float  floatx16 __attribute__((ext_vector_type(16)));

// Workspace layout (bytes):
//   Kq   bf16 [2][8192][16]   offset 0        (512 KB)  scaled by sqrt(log2 e)
//   Vswz bf16 [2][8192][32]   offset 524288   (1 MB)    B-frag swizzled order
//   Opart f32 [2*8192][split][32]  offset 1572864
//   Lpart f32 [2*8192][split]      after Opart
#define KQ_ELEMS (2 * 8192 * 16)
#define PART_OFF 1572864
#define SQRT_LOG2E 1.2011224087864498f

// ---------------- Kernel A: projections ----------------
__global__ __launch_bounds__(256) void proj_kernel(
    const float* __restrict__ in, const float* __restrict__ W1,
    const float* __restrict__ b1, const float* __restrict__ W2,
    const float* __restrict__ b2,
    __hip_bfloat16* __restrict__ Kq, __hip_bfloat16* __restrict__ Vswz)
{
    __shared__ float Xs[32][32];
    __shared__ float W1s[16 * 32];
    __shared__ float W2s[32 * 32];
    const int t = threadIdx.x;
    const int bid = blockIdx.x;       // 0..511
    const int b = bid >> 8;
    const int hw = bid & 255;

    {
        int l = t >> 3, cs = (t & 7) * 4;
        float4 v = *(const float4*)(in + (((size_t)b * 32 + l) * 256 + hw) * 32 + cs);
        *(float4*)&Xs[l][cs] = v;
    }
    if (t < 128) *(float4*)&W1s[t * 4] = *(const float4*)(W1 + t * 4);
    *(float4*)&W2s[t * 4] = *(const float4*)(W2 + t * 4);
    __syncthreads();

    const int c = t & 31;
    const int g = t >> 5;             // 0..7

#pragma unroll
    for (int oo = 0; oo < 2; ++oo) {
        int o = g * 2 + oo;           // 0..15
        float acc = b1[o];
#pragma unroll
        for (int l = 0; l < 32; ++l) acc += W1s[o * 32 + l] * Xs[l][c];
        int k = c >> 1;
        int i = (c & 1) * 4096 + o * 256 + hw;
        Kq[((size_t)b * 8192 + i) * 16 + k] = __float2bfloat16(acc * SQRT_LOG2E);
    }
#pragma unroll
    for (int oo = 0; oo < 4; ++oo) {
        int o = g * 4 + oo;           // 0..31
        float acc = b2[o];
#pragma unroll
        for (int l = 0; l < 32; ++l) acc += W2s[o * 32 + l] * Xs[l][c];
        // position j = o*256 + hw, channel = c; B-frag swizzle:
        // flat = jt*1024 + gg*256 + h*128 + c*4 + idx
        int j = o * 256 + hw;
        int jt = j >> 5, rem = j & 31;
        int gg = rem >> 3, h = (rem >> 2) & 1, idx = rem & 3;
        Vswz[(size_t)b * 262144 + jt * 1024 + gg * 256 + h * 128 + c * 4 + idx] =
            __float2bfloat16(acc);
    }
}

// ---------------- Kernel B: flash attention, LDS-free, coalesced, dual-chain ----------------
// block = 256 thr (4 waves), each wave owns 32 i-rows. grid = 2 * 64 * split.
__global__ __launch_bounds__(256) void flash_kernel(
    const __hip_bfloat16* __restrict__ Kq, const __hip_bfloat16* __restrict__ Vswz,
    float* __restrict__ Opart, float* __restrict__ Lpart, int lsplit)
{
    const int t = threadIdx.x;
    const int lane = t & 63;
    const int wv = t >> 6;            // 0..3
    const int m = lane & 31;
    const int h = lane >> 5;          // 0/1

    const int bid = blockIdx.x;
    const int split = 1 << lsplit;
    const int s = bid & (split - 1);
    const int itile = (bid >> lsplit) & 63;
    const int b = bid >> (lsplit + 6);
    const int i0 = itile * 128 + wv * 32;
    const int jcount = 8192 >> lsplit;
    const int niter = jcount >> 5;
    const int jt0 = (s * jcount) >> 5;   // first 32-j tile index

    const __hip_bfloat16* Kb = Kq + (size_t)b * 8192 * 16;
    const __hip_bfloat16* Vb = Vswz + (size_t)b * 262144 + h * 128 + m * 4;

    // Q B-frag (regs): B[k=8h+idx][n=m] = Kq[i0+m][8h+idx]
    const bf16x8 bq = *(const bf16x8*)(Kb + (size_t)(i0 + m) * 16 + h * 8);

    floatx16 oa = {}, ob = {};
    float l0 = 0.f, l1 = 0.f, l2 = 0.f, l3 = 0.f;

    // prefetch it = 0
    bf16x8 ak = *(const bf16x8*)(Kb + (size_t)(jt0 * 32 + m) * 16 + h * 8);
    s16x4 vf0 = *(const s16x4*)(Vb + (size_t)jt0 * 1024 + 0);
    s16x4 vf1 = *(const s16x4*)(Vb + (size_t)jt0 * 1024 + 256);
    s16x4 vf2 = *(const s16x4*)(Vb + (size_t)jt0 * 1024 + 512);
    s16x4 vf3 = *(const s16x4*)(Vb + (size_t)jt0 * 1024 + 768);

    for (int it = 0; it < niter; ++it) {
        // prefetch it+1 (clamped: last iter re-loads itself, harmless)
        const int jtn = jt0 + (it + 1 < niter ? it + 1 : it);
        bf16x8 ak_n = *(const bf16x8*)(Kb + (size_t)(jtn * 32 + m) * 16 + h * 8);
        s16x4 vn0 = *(const s16x4*)(Vb + (size_t)jtn * 1024 + 0);
        s16x4 vn1 = *(const s16x4*)(Vb + (size_t)jtn * 1024 + 256);
        s16x4 vn2 = *(const s16x4*)(Vb + (size_t)jtn * 1024 + 512);
        s16x4 vn3 = *(const s16x4*)(Vb + (size_t)jtn * 1024 + 768);

        // S^T(32j x 32i) = K(A) x Q(B), K=16 exact
        floatx16 sc = __builtin_amdgcn_mfma_f32_32x32x16_bf16(ak, bq, (floatx16){}, 0, 0, 0);

        // P = 2^S ; reg 4g+idx holds j_loc = 8g+4h+idx == 32x32x8 A-layout.
        // g=0,1 -> oa ; g=2,3 -> ob  (two independent accumulator chains)
#pragma unroll
        for (int g = 0; g < 4; ++g) {
            bf16x4v pb;
            float e0 = __builtin_amdgcn_exp2f(sc[4 * g + 0]);
            float e1 = __builtin_amdgcn_exp2f(sc[4 * g + 1]);
            float e2 = __builtin_amdgcn_exp2f(sc[4 * g + 2]);
            float e3 = __builtin_amdgcn_exp2f(sc[4 * g + 3]);
            l0 += e0; l1 += e1; l2 += e2; l3 += e3;
            pb[0] = (__bf16)e0; pb[1] = (__bf16)e1; pb[2] = (__bf16)e2; pb[3] = (__bf16)e3;
            s16x4 vf = (g == 0) ? vf0 : (g == 1) ? vf1 : (g == 2) ? vf2 : vf3;
            if (g < 2)
                oa = __builtin_amdgcn_mfma_f32_32x32x8bf16_1k(
                         __builtin_bit_cast(s16x4, pb), vf, oa, 0, 0, 0);
            else
                ob = __builtin_amdgcn_mfma_f32_32x32x8bf16_1k(
                         __builtin_bit_cast(s16x4, pb), vf, ob, 0, 0, 0);
        }
        ak = ak_n; vf0 = vn0; vf1 = vn1; vf2 = vn2; vf3 = vn3;
    }

    oa = oa + ob;
    float l = (l0 + l1) + (l2 + l3);
    l += __shfl_xor(l, 32);

    // write partials. oa reg r -> row i_loc=(r&3)+8*(r>>2)+4h, col c=m
#pragma unroll
    for (int r = 0; r < 16; ++r) {
        int iloc = (r & 3) + 8 * (r >> 2) + 4 * h;
        size_t row = (size_t)b * 8192 + i0 + iloc;
        Opart[((row << lsplit) | s) * 32 + m] = oa[r];
    }
    if (h == 0)
        Lpart[(((size_t)b * 8192 + i0 + m) << lsplit) | s] = l;
}

// ---------------- Kernel C: combine partials + epilogue ----------------
__global__ __launch_bounds__(256) void combine_kernel(
    const float* __restrict__ Opart, const float* __restrict__ Lpart,
    const float* __restrict__ in, const float* __restrict__ gamma,
    float* __restrict__ out, int lsplit)
{
    const int t = threadIdx.x;
    const int c = t & 31;
    const size_t row = (size_t)blockIdx.x * 8 + (t >> 5);
    const int split = 1 << lsplit;

    float acc = 0.f, l = 0.f;
    for (int s = 0; s < split; ++s) {
        acc += Opart[((row << lsplit) | s) * 32 + c];
        l += Lpart[(row << lsplit) | s];
    }
    size_t idx = row * 32 + c;
    out[idx] = (acc / l) * gamma[0] + in[idx];
}

extern "C" void kernel_launch(void* const* d_in, const int* in_sizes, int n_in,
                              void* d_out, int out_size, void* d_ws, size_t ws_size,
                              hipStream_t stream) {
    const float* in = (const float*)d_in[0];
    const float* W1 = (const float*)d_in[1];
    const float* b1 = (const float*)d_in[2];
    const float* W2 = (const float*)d_in[3];
    const float* b2 = (const float*)d_in[4];
    const float* gamma = (const float*)d_in[5];
    float* out = (float*)d_out;

    __hip_bfloat16* Kq = (__hip_bfloat16*)d_ws;
    __hip_bfloat16* Vswz = Kq + KQ_ELEMS;

    // pick largest split (pow2 <= 8) whose partials fit in ws
    int lsplit = 3;
    while (lsplit > 1) {
        size_t need = (size_t)PART_OFF + ((size_t)16384 << lsplit) * 33 * 4;
        if (need <= ws_size) break;
        --lsplit;
    }
    float* Opart = (float*)((char*)d_ws + PART_OFF);
    float* Lpart = Opart + ((size_t)16384 << lsplit) * 32;

    proj_kernel<<<512, 256, 0, stream>>>(in, W1, b1, W2, b2, Kq, Vswz);
    flash_kernel<<<2 * 64 * (1 << lsplit), 256, 0, stream>>>(Kq, Vswz, Opart, Lpart, lsplit);
    combine_kernel<<<2048, 256, 0, stream>>>(Opart, Lpart, in, gamma, out, lsplit);
}

// Round 5
// 112.348 us; speedup vs baseline: 2.3667x; 1.0286x over previous
//
#include <hip/hip_runtime.h>
#include <hip/hip_bf16.h>
#include <math.h>

typedef __bf16 bf16x8 __attribute__((ext_vector_type(8)));
typedef __bf16 bf16x4v __attribute__((ext_vector_type(4)));
typedef short  s16x4  __attribute__((ext_vector_type(4)));
typedef float  floatx16 __attribute__((ext_vector_type(16)));

// Workspace layout (bytes):
//   Kq   bf16 [2][8192][16]   offset 0        (512 KB)  scaled by sqrt(log2 e)
//   Vswz bf16 [2][8192][32]   offset 524288   (1 MB)    B-frag swizzled order
//   Oacc f32  [2*8192][32]    offset 1572864  (2 MB)    atomic accumulator
//   Lacc f32  [2*8192]        offset 3669888  (64 KB)
#define KQ_ELEMS (2 * 8192 * 16)
#define OACC_OFF 1572864
#define ACC_FLOATS (16384 * 32 + 16384)   // 540672 floats (Oacc + Lacc contiguous)
#define SQRT_LOG2E 1.2011224087864498f
#define LSPLIT 4

// ---------------- Kernel A: zero accumulators + projections ----------------
__global__ __launch_bounds__(256) void proj_kernel(
    const float* __restrict__ in, const float* __restrict__ W1,
    const float* __restrict__ b1, const float* __restrict__ W2,
    const float* __restrict__ b2,
    __hip_bfloat16* __restrict__ Kq, __hip_bfloat16* __restrict__ Vswz,
    float* __restrict__ acc0)
{
    __shared__ float Xs[32][32];
    __shared__ float W1s[16 * 32];
    __shared__ float W2s[32 * 32];
    const int t = threadIdx.x;
    const int bid = blockIdx.x;       // 0..511
    const int b = bid >> 8;
    const int hw = bid & 255;

    // zero the 540672-float accumulator region (Oacc + Lacc)
    {
        int gid = bid * 256 + t;                       // 0..131071
        *(float4*)(acc0 + (size_t)gid * 4) = make_float4(0.f, 0.f, 0.f, 0.f);
        if (gid < 4096)
            *(float4*)(acc0 + 524288 + (size_t)gid * 4) = make_float4(0.f, 0.f, 0.f, 0.f);
    }

    {
        int l = t >> 3, cs = (t & 7) * 4;
        float4 v = *(const float4*)(in + (((size_t)b * 32 + l) * 256 + hw) * 32 + cs);
        *(float4*)&Xs[l][cs] = v;
    }
    if (t < 128) *(float4*)&W1s[t * 4] = *(const float4*)(W1 + t * 4);
    *(float4*)&W2s[t * 4] = *(const float4*)(W2 + t * 4);
    __syncthreads();

    const int c = t & 31;
    const int g = t >> 5;             // 0..7

#pragma unroll
    for (int oo = 0; oo < 2; ++oo) {
        int o = g * 2 + oo;           // 0..15
        float acc = b1[o];
#pragma unroll
        for (int l = 0; l < 32; ++l) acc += W1s[o * 32 + l] * Xs[l][c];
        int k = c >> 1;
        int i = (c & 1) * 4096 + o * 256 + hw;
        Kq[((size_t)b * 8192 + i) * 16 + k] = __float2bfloat16(acc * SQRT_LOG2E);
    }
#pragma unroll
    for (int oo = 0; oo < 4; ++oo) {
        int o = g * 4 + oo;           // 0..31
        float acc = b2[o];
#pragma unroll
        for (int l = 0; l < 32; ++l) acc += W2s[o * 32 + l] * Xs[l][c];
        // position j = o*256 + hw, channel c; B-frag swizzle:
        // flat = jt*1024 + gg*256 + h*128 + c*4 + idx
        int j = o * 256 + hw;
        int jt = j >> 5, rem = j & 31;
        int gg = rem >> 3, h = (rem >> 2) & 1, idx = rem & 3;
        Vswz[(size_t)b * 262144 + jt * 1024 + gg * 256 + h * 128 + c * 4 + idx] =
            __float2bfloat16(acc);
    }
}

// ---------------- Kernel B: flash attention, LDS-free, atomic-accumulate ----------------
// block = 256 thr (4 waves), each wave owns 32 i-rows. grid = 2 * 64 * 16 = 2048.
__global__ __launch_bounds__(256) void flash_kernel(
    const __hip_bfloat16* __restrict__ Kq, const __hip_bfloat16* __restrict__ Vswz,
    float* __restrict__ Oacc, float* __restrict__ Lacc)
{
    const int t = threadIdx.x;
    const int lane = t & 63;
    const int wv = t >> 6;            // 0..3
    const int m = lane & 31;
    const int h = lane >> 5;          // 0/1

    const int bid = blockIdx.x;
    const int s = bid & 15;
    const int itile = (bid >> LSPLIT) & 63;
    const int b = bid >> (LSPLIT + 6);
    const int i0 = itile * 128 + wv * 32;
    const int niter = 512 >> 5;       // 16 tiles of 32 j
    const int jt0 = s * niter;

    const __hip_bfloat16* Kb = Kq + (size_t)b * 8192 * 16;
    const __hip_bfloat16* Vb = Vswz + (size_t)b * 262144 + h * 128 + m * 4;

    // Q B-frag (regs): B[k=8h+idx][n=m] = Kq[i0+m][8h+idx]
    const bf16x8 bq = *(const bf16x8*)(Kb + (size_t)(i0 + m) * 16 + h * 8);

    floatx16 oa = {}, ob = {};
    float2 l01 = {0.f, 0.f}, l23 = {0.f, 0.f};

    // prefetch it = 0
    bf16x8 ak = *(const bf16x8*)(Kb + (size_t)(jt0 * 32 + m) * 16 + h * 8);
    s16x4 vf0 = *(const s16x4*)(Vb + (size_t)jt0 * 1024 + 0);
    s16x4 vf1 = *(const s16x4*)(Vb + (size_t)jt0 * 1024 + 256);
    s16x4 vf2 = *(const s16x4*)(Vb + (size_t)jt0 * 1024 + 512);
    s16x4 vf3 = *(const s16x4*)(Vb + (size_t)jt0 * 1024 + 768);

    for (int it = 0; it < niter; ++it) {
        const int jtn = jt0 + (it + 1 < niter ? it + 1 : it);
        bf16x8 ak_n = *(const bf16x8*)(Kb + (size_t)(jtn * 32 + m) * 16 + h * 8);
        s16x4 vn0 = *(const s16x4*)(Vb + (size_t)jtn * 1024 + 0);
        s16x4 vn1 = *(const s16x4*)(Vb + (size_t)jtn * 1024 + 256);
        s16x4 vn2 = *(const s16x4*)(Vb + (size_t)jtn * 1024 + 512);
        s16x4 vn3 = *(const s16x4*)(Vb + (size_t)jtn * 1024 + 768);

        // S^T(32j x 32i) = K(A) x Q(B), K=16 exact
        floatx16 sc = __builtin_amdgcn_mfma_f32_32x32x16_bf16(ak, bq, (floatx16){}, 0, 0, 0);

        // P = 2^S ; reg 4g+idx holds j_loc = 8g+4h+idx == 32x32x8 A-layout.
#pragma unroll
        for (int g = 0; g < 4; ++g) {
            bf16x4v pb;
            float e0 = __builtin_amdgcn_exp2f(sc[4 * g + 0]);
            float e1 = __builtin_amdgcn_exp2f(sc[4 * g + 1]);
            float e2 = __builtin_amdgcn_exp2f(sc[4 * g + 2]);
            float e3 = __builtin_amdgcn_exp2f(sc[4 * g + 3]);
            l01.x += e0; l01.y += e1; l23.x += e2; l23.y += e3;
            pb[0] = (__bf16)e0; pb[1] = (__bf16)e1; pb[2] = (__bf16)e2; pb[3] = (__bf16)e3;
            s16x4 vf = (g == 0) ? vf0 : (g == 1) ? vf1 : (g == 2) ? vf2 : vf3;
            if (g < 2)
                oa = __builtin_amdgcn_mfma_f32_32x32x8bf16_1k(
                         __builtin_bit_cast(s16x4, pb), vf, oa, 0, 0, 0);
            else
                ob = __builtin_amdgcn_mfma_f32_32x32x8bf16_1k(
                         __builtin_bit_cast(s16x4, pb), vf, ob, 0, 0, 0);
        }
        ak = ak_n; vf0 = vn0; vf1 = vn1; vf2 = vn2; vf3 = vn3;
    }

    oa = oa + ob;
    float l = (l01.x + l01.y) + (l23.x + l23.y);
    l += __shfl_xor(l, 32);

    // atomic-accumulate partials (plain sums: no max-rescaling in this scheme)
#pragma unroll
    for (int r = 0; r < 16; ++r) {
        int iloc = (r & 3) + 8 * (r >> 2) + 4 * h;
        size_t row = (size_t)b * 8192 + i0 + iloc;
        unsafeAtomicAdd(&Oacc[row * 32 + m], oa[r]);
    }
    if (h == 0)
        unsafeAtomicAdd(&Lacc[(size_t)b * 8192 + i0 + m], l);
}

// ---------------- Kernel C: normalize + epilogue ----------------
__global__ __launch_bounds__(256) void finalize_kernel(
    const float* __restrict__ Oacc, const float* __restrict__ Lacc,
    const float* __restrict__ in, const float* __restrict__ gamma,
    float* __restrict__ out)
{
    const int t = threadIdx.x;
    const int c = t & 31;
    const size_t row = (size_t)blockIdx.x * 8 + (t >> 5);
    size_t idx = row * 32 + c;
    out[idx] = (Oacc[idx] / Lacc[row]) * gamma[0] + in[idx];
}

extern "C" void kernel_launch(void* const* d_in, const int* in_sizes, int n_in,
                              void* d_out, int out_size, void* d_ws, size_t ws_size,
                              hipStream_t stream) {
    const float* in = (const float*)d_in[0];
    const float* W1 = (const float*)d_in[1];
    const float* b1 = (const float*)d_in[2];
    const float* W2 = (const float*)d_in[3];
    const float* b2 = (const float*)d_in[4];
    const float* gamma = (const float*)d_in[5];
    float* out = (float*)d_out;

    __hip_bfloat16* Kq = (__hip_bfloat16*)d_ws;
    __hip_bfloat16* Vswz = Kq + KQ_ELEMS;
    float* Oacc = (float*)((char*)d_ws + OACC_OFF);
    float* Lacc = Oacc + 16384 * 32;

    proj_kernel<<<512, 256, 0, stream>>>(in, W1, b1, W2, b2, Kq, Vswz, Oacc);
    flash_kernel<<<2 * 64 * (1 << LSPLIT), 256, 0, stream>>>(Kq, Vswz, Oacc, Lacc);
    finalize_kernel<<<2048, 256, 0, stream>>>(Oacc, Lacc, in, gamma, out);
}